// Round 12
// baseline (34071.786 us; speedup 1.0000x reference)
//
#include <hip/hip_runtime.h>
#include <hip/hip_bf16.h>
#include <math.h>

// Problem dims
#define B_   128
#define T_   800
#define H_   512
#define K_   10
#define C_   80
#define U_   64
#define IN_  3

// Decomposition: 4 groups x 32 batches; 32 blocks/group; each block owns 16 units (64 gate rows)
#define NG   4
#define BPG  32
#define BT   32
#define NT   256
#define KROW 608            // LDS padded K extent (592 real + 16 zero)
#define HB   512            // gbuf row width (h only)

// ws layout (4-byte units): gbuf[2][128][512] u32 | pps[2][NG][BPG][960] f32 | flags
#define WS_PPS_F   (2*B_*HB)
#define WS_BAR_F   (WS_PPS_F + 2*NG*BPG*960)
#define WS_TOTAL_F (WS_BAR_F + NG*4*32)

// out layout (f32 elements): h_seq | w_seq | phi_seq
#define OFF_H    0ull
#define OFF_W    ((size_t)B_ * T_ * H_)
#define OFF_PHI  (OFF_W + (size_t)B_ * T_ * C_)

typedef __attribute__((ext_vector_type(8))) short short8;
typedef __attribute__((ext_vector_type(4))) float f32x4;

// XOR swizzle of 16B units within each 64B span, keyed by row
#define SWZB(row)    (((row) ^ ((row) >> 2)) & 3)
#define SWIDX(row,k) ((row)*KROW + ((((k) >> 3) ^ SWZB(row)) << 3) + ((k) & 7))
#define LDFRAG(arr,row,u) (*(const short8*)&(arr)[(row)*KROW + (((u) ^ SWZB(row)) << 3)])

// ---- sync primitives (r5-proven recipe: bypass writes + vm fence + relaxed flags,
//      single poller + single acquire-inv, then plain cached loads) ----
__device__ __forceinline__ void stb_u32(unsigned* p, unsigned v) {
  asm volatile("global_store_dword %0, %1, off sc0 sc1" :: "v"(p), "v"(v) : "memory");
}
__device__ __forceinline__ void stb_f32(float* p, float v) {
  asm volatile("global_store_dword %0, %1, off sc0 sc1" :: "v"(p), "v"(v) : "memory");
}
__device__ __forceinline__ void fence_vm() {
  asm volatile("s_waitcnt vmcnt(0)" ::: "memory");
}
__device__ __forceinline__ void flag_add(unsigned* p) {
  __hip_atomic_fetch_add(p, 1u, __ATOMIC_RELAXED, __HIP_MEMORY_SCOPE_AGENT);
}
__device__ __forceinline__ unsigned flag_sum4(unsigned* base) {
  unsigned s0 = __hip_atomic_load(base +  0, __ATOMIC_RELAXED, __HIP_MEMORY_SCOPE_AGENT);
  unsigned s1 = __hip_atomic_load(base + 32, __ATOMIC_RELAXED, __HIP_MEMORY_SCOPE_AGENT);
  unsigned s2 = __hip_atomic_load(base + 64, __ATOMIC_RELAXED, __HIP_MEMORY_SCOPE_AGENT);
  unsigned s3 = __hip_atomic_load(base + 96, __ATOMIC_RELAXED, __HIP_MEMORY_SCOPE_AGENT);
  return (s0 + s1) + (s2 + s3);
}
__device__ __forceinline__ void acq_fence(unsigned* p) {
  (void)__hip_atomic_load(p, __ATOMIC_ACQUIRE, __HIP_MEMORY_SCOPE_AGENT);
}
__device__ __forceinline__ float sigmoidf_(float v) { return 1.0f / (1.0f + expf(-v)); }
__device__ __forceinline__ unsigned pack_hl(float v) {
  unsigned hb = __float_as_uint(v) >> 16;
  float rs = v - __uint_as_float(hb << 16);
  unsigned lb = __float_as_uint(rs) >> 16;
  return (hb << 16) | lb;
}
__device__ __forceinline__ float comb_hl(short h, short l) {
  return __uint_as_float((unsigned)(unsigned short)h << 16) +
         __uint_as_float((unsigned)(unsigned short)l << 16);
}

__global__ void __launch_bounds__(256, 2)
init_ws_kernel(float* __restrict__ ws) {
  size_t i = (size_t)blockIdx.x * 256 + threadIdx.x;
  const size_t n = (size_t)WS_TOTAL_F;
  const size_t stride = (size_t)gridDim.x * 256;
  for (; i < n; i += stride) ws[i] = 0.0f;
}

__global__ void __launch_bounds__(NT, 1)   // 4 waves = 1 wave/SIMD: allocator gives ~200+ VGPRs
                                           // (r8-proven); 8-wave blocks capped us at 128 + spill
graves_kernel(const float* __restrict__ x,       // [B][T][3]
              const int*   __restrict__ sent,    // [B][U]
              const float* __restrict__ smask,   // [B][U]
              const float* __restrict__ W_ih,    // [2048][83]
              const float* __restrict__ W_hh,    // [2048][512]
              const float* __restrict__ b_ih,    // [2048]
              const float* __restrict__ b_hh,    // [2048]
              const float* __restrict__ W_win,   // [30][512]
              const float* __restrict__ b_win,   // [30]
              float* __restrict__ out,
              float* __restrict__ ws)
{
  const int tid = threadIdx.x;
  const int bid = blockIdx.x;
  // XCD-local grouping heuristic: group g lives on XCDs {2g, 2g+1} (any bijection is correct).
  const int xcd  = bid & 7, slot = bid >> 3;     // slot 0..15
  const int g    = xcd >> 1;
  const int ub   = ((xcd & 1) << 4) | slot;      // 0..31
  const int b0   = g * BT;
  const int u0   = ub * 16;                      // first unit owned

  unsigned* gbuf = (unsigned*)ws;
  float*    pps  = ws + WS_PPS_F;
  unsigned* c1l  = (unsigned*)(ws + WS_BAR_F) + (size_t)g * 128;  // 4 lines x 8 arrivals/step

  // ---- LDS: ~87 KB -> 1 block/CU ----
  __shared__ __align__(16) short shi[32 * KROW];   // 38,912 B  state hi
  __shared__ __align__(16) short slo[32 * KROW];   // 38,912 B  state lo
  __shared__ float pbufS[32][32];                  //  4,096 B  window params (alpha|beta|kappa)
  __shared__ float hT[16 * 32];                    //  2,048 B  own units' exact f32 h  [unit][batch]
  __shared__ float wwin[16 * 30];                  //  1,920 B  W_win slice (own units, f32)
  __shared__ float xwb[64][4];                     //  1,024 B  x-weights + bias per gate row

  // wave identity
  const int lane = tid & 63;
  const int wid  = tid >> 6;         // 4 waves; wave owns gate rows wid*16..wid*16+15 (full k)
  const int r16  = lane & 15;
  const int g4   = lane >> 4;

  // ---- one-time LDS staging ----
  for (int idx = tid; idx < 32 * 16; idx += NT) {  // zero state pad cols 592..607 (never rewritten)
    const int b2 = idx >> 4, k = (H_ + C_) + (idx & 15);
    shi[SWIDX(b2, k)] = 0; slo[SWIDX(b2, k)] = 0;
  }
  if (tid < 64) {                                   // xwb: row = unit_l*4 + gate
    const int uu = tid >> 2, gate = tid & 3, gr = gate * H_ + u0 + uu;
    xwb[tid][0] = W_ih[(size_t)gr * (IN_ + C_) + 0];
    xwb[tid][1] = W_ih[(size_t)gr * (IN_ + C_) + 1];
    xwb[tid][2] = W_ih[(size_t)gr * (IN_ + C_) + 2];
    xwb[tid][3] = b_ih[gr] + b_hh[gr];
  }
  for (int idx = tid; idx < 16 * 30; idx += NT) {   // W_win slice (exact f32)
    const int uu = idx / 30, j = idx - uu * 30;
    wwin[idx] = W_win[(size_t)j * H_ + u0 + uu];
  }

  // ---- one-time: gate-weight A-fragments -> persistent VGPRs (split bf16, 152 VGPRs) ----
  // wave's rows: lrow = wid*16 + r16 -> (unit_l = lrow>>2, gate = lrow&3)
  short8 wh[19], wl[19];
  {
    const int lrow = wid * 16 + r16;
    const int uuA = lrow >> 2, gateA = lrow & 3;
    const int gr = gateA * H_ + u0 + uuA;
    #pragma unroll
    for (int ks = 0; ks < 19; ++ks) {
      short8 h8 = {0,0,0,0,0,0,0,0}, l8 = h8;
      #pragma unroll
      for (int e = 0; e < 8; ++e) {
        const int k = ks * 32 + g4 * 8 + e;
        float wv = 0.0f;
        if (k < H_)           wv = W_hh[(size_t)gr * H_ + k];
        else if (k < H_ + C_) wv = W_ih[(size_t)gr * (IN_ + C_) + IN_ + (k - H_)];
        const unsigned hb = __float_as_uint(wv) >> 16;
        const float rs = wv - __uint_as_float(hb << 16);
        h8[e] = (short)hb; l8[e] = (short)(__float_as_uint(rs) >> 16);
      }
      wh[ks] = h8; wl[ks] = l8;
    }
  }

  // ---- per-thread sent/mask for phi/scatter: thread = (pb = tid>>3, ug = tid&7), u = ug*8+i ----
  const int pb = tid >> 3, ug = tid & 7;
  float msk[8]; int snt[8];
  #pragma unroll
  for (int i = 0; i < 8; ++i) {
    msk[i] = smask[(size_t)(b0 + pb) * U_ + ug * 8 + i];
    snt[i] = sent [(size_t)(b0 + pb) * U_ + ug * 8 + i];
  }
  __syncthreads();

  float cr0 = 0.0f, cr1 = 0.0f;      // c-state (per thread: unit wid*4+g4, batches r16 / 16+r16)
  float kp0 = 0.f, kp1 = 0.f, kp2 = 0.f, kp3 = 0.f;  // kappa regs per P3 round

#define GSTEP(ks) { \
    const int uu_ = (ks) * 4 + g4; \
    const short8 bh0 = LDFRAG(shi, r16, uu_); \
    const short8 bl0 = LDFRAG(slo, r16, uu_); \
    const short8 bh1 = LDFRAG(shi, 16 + r16, uu_); \
    const short8 bl1 = LDFRAG(slo, 16 + r16, uu_); \
    a0 = __builtin_amdgcn_mfma_f32_16x16x32_bf16(wh[ks], bh0, a0, 0, 0, 0); \
    a0 = __builtin_amdgcn_mfma_f32_16x16x32_bf16(wh[ks], bl0, a0, 0, 0, 0); \
    a0 = __builtin_amdgcn_mfma_f32_16x16x32_bf16(wl[ks], bh0, a0, 0, 0, 0); \
    a1 = __builtin_amdgcn_mfma_f32_16x16x32_bf16(wh[ks], bh1, a1, 0, 0, 0); \
    a1 = __builtin_amdgcn_mfma_f32_16x16x32_bf16(wh[ks], bl1, a1, 0, 0, 0); \
    a1 = __builtin_amdgcn_mfma_f32_16x16x32_bf16(wl[ks], bh1, a1, 0, 0, 0); \
  }

#define SUMR(r, KP) { \
    const int item = tid + 256 * (r); \
    if (item < 960) { \
      const int b2 = item / 30, j = item - b2 * 30; \
      float v = 0.0f; \
      _Pragma("unroll") \
      for (int sh = 0; sh < BPG; ++sh) v += ppsR[sh * 960 + item]; \
      float ev = __expf(v + b_win[j]); \
      if (j >= 20) { ev += (KP); (KP) = ev; } \
      pbufS[b2][j] = ev; \
    } }

#define PUBR(r) { \
    const int item = tid + 256 * (r); \
    if (item < 960) { \
      const int b2 = item / 30, j = item - b2 * 30; \
      float s = 0.0f; \
      _Pragma("unroll") \
      for (int uu = 0; uu < 16; ++uu) s = fmaf(wwin[uu * 30 + j], hT[uu * 32 + b2], s); \
      stb_f32(ppsW + item, s); \
    } }

  for (int t = 0; t <= T_; ++t) {
    const unsigned* pIn  = gbuf + (size_t)((t & 1) ^ 1) * (B_ * HB);
    unsigned*       pOut = gbuf + (size_t)(t & 1) * (B_ * HB);

    // ---- P1: single sync point, 32-wide; single poller, single acquire-inv ----
    if (t > 0 && tid == 0) {
      const unsigned tgt = 32u * (unsigned)t;
      while (flag_sum4(c1l) < tgt) __builtin_amdgcn_s_sleep(1);
      acq_fence(c1l);
    }
    __syncthreads();

    // ---- P2: stage h(t-1) into LDS (split bf16, swizzled); zero window cols; x prefetch ----
    float xv00=0.f,xv01=0.f,xv02=0.f, xv10=0.f,xv11=0.f,xv12=0.f;
    {
      const int sb = tid & 31, seg = tid >> 5;     // 8 segs x 64 k
      if (t < T_) {
        const uint4* grow = (const uint4*)(pIn + (size_t)(b0 + sb) * HB + seg * 64);
        #pragma unroll
        for (int half = 0; half < 2; ++half) {
          uint4 v[8];
          #pragma unroll
          for (int i = 0; i < 8; ++i) v[i] = grow[half * 8 + i];
          #pragma unroll
          for (int i = 0; i < 8; ++i) {
            const int k = seg * 64 + half * 32 + i * 4;
            const int idx = SWIDX(sb, k);
            const unsigned h01 = (v[i].x >> 16) | ((v[i].y >> 16) << 16);
            const unsigned h23 = (v[i].z >> 16) | ((v[i].w >> 16) << 16);
            const unsigned l01 = (v[i].x & 0xffffu) | ((v[i].y & 0xffffu) << 16);
            const unsigned l23 = (v[i].z & 0xffffu) | ((v[i].w & 0xffffu) << 16);
            *(uint2*)&shi[idx] = make_uint2(h01, h23);
            *(uint2*)&slo[idx] = make_uint2(l01, l23);
          }
        }
        const float* xp0 = x + ((size_t)(b0 + r16) * T_ + t) * IN_;
        const float* xp1 = x + ((size_t)(b0 + 16 + r16) * T_ + t) * IN_;
        xv00 = xp0[0]; xv01 = xp0[1]; xv02 = xp0[2];
        xv10 = xp1[0]; xv11 = xp1[1]; xv12 = xp1[2];
      }
      #pragma unroll
      for (int i = 0; i < 10; ++i) {               // zero window cols (scatter accumulates)
        const int c = seg * 10 + i;
        const int idx = SWIDX(sb, H_ + c);
        shi[idx] = 0; slo[idx] = 0;
      }
    }
    __syncthreads();

    // ---- P3: window(t-1) — sum 32 exact-f32 partial slots (fixed order => deterministic) ----
    if (t >= 1) {
      const float* ppsR = pps + (size_t)(((t - 1) & 1) * NG + g) * (BPG * 960);
      SUMR(0, kp0) SUMR(1, kp1) SUMR(2, kp2) SUMR(3, kp3)
      __syncthreads();

      // phi per (pb, ug): 8 u-values; params hoisted to registers
      float al[10], be[10], ka[10];
      #pragma unroll
      for (int k2 = 0; k2 < 10; ++k2) {
        al[k2] = pbufS[pb][k2];
        be[k2] = pbufS[pb][10 + k2];
        ka[k2] = pbufS[pb][20 + k2];
      }
      float ph[8];
      #pragma unroll
      for (int i = 0; i < 8; ++i) {
        const float fu = (float)(ug * 8 + i);
        float s = 0.0f;
        #pragma unroll
        for (int k2 = 0; k2 < 10; ++k2) {
          const float d = ka[k2] - fu;
          s = fmaf(al[k2], __expf(-be[k2] * d * d), s);
        }
        ph[i] = s;
      }
      if (pb == ub) {                              // raw phi out (block's batch)
        #pragma unroll
        for (int i = 0; i < 8; ++i)
          out[OFF_PHI + ((size_t)(b0 + pb) * T_ + (t - 1)) * U_ + ug * 8 + i] = ph[i];
      }
      #pragma unroll
      for (int i = 0; i < 8; ++i) ph[i] *= msk[i];

      // scatter into state LDS window cols. Rounds over ug serialize same-row writers
      // (waves own disjoint pb rows; DS ops within a wave are ordered).
      #pragma unroll
      for (int r = 0; r < 8; ++r) {
        if (ug == r) {
          #pragma unroll
          for (int i = 0; i < 8; ++i) {
            const int idx = SWIDX(pb, H_ + snt[i]);
            float cur = comb_hl(shi[idx], slo[idx]) + ph[i];
            const unsigned pk = pack_hl(cur);
            shi[idx] = (short)(pk >> 16);
            slo[idx] = (short)(pk & 0xffffu);
          }
        }
        asm volatile("" ::: "memory");
      }
      __syncthreads();
      if (tid < C_) {                              // window out (block's batch)
        const int idx = SWIDX(ub, H_ + tid);
        out[OFF_W + ((size_t)(b0 + ub) * T_ + (t - 1)) * C_ + tid] = comb_hl(shi[idx], slo[idx]);
      }
    }
    if (t == T_) break;                            // epilogue done

    // ---- P4: full gate GEMM, k 0..607; wave owns 16 rows x full k (no cross-wave reduce) ----
    f32x4 a0 = {0.f, 0.f, 0.f, 0.f}, a1 = {0.f, 0.f, 0.f, 0.f};
    GSTEP(0)  GSTEP(1)  GSTEP(2)  GSTEP(3)  GSTEP(4)
    GSTEP(5)  GSTEP(6)  GSTEP(7)  GSTEP(8)  GSTEP(9)
    GSTEP(10) GSTEP(11) GSTEP(12) GSTEP(13) GSTEP(14)
    GSTEP(15) GSTEP(16) GSTEP(17) GSTEP(18)

    // ---- P5: LSTM pointwise, fully wave-local (D row = g4*4+e => unit wid*4+g4, gate e) ----
    {
      const int unit = wid * 4 + g4;
      const int prow = wid * 16 + g4 * 4;
      #pragma unroll
      for (int bt2 = 0; bt2 < 2; ++bt2) {
        const f32x4 acc = bt2 ? a1 : a0;
        const int batch = bt2 * 16 + r16;
        const float X0 = bt2 ? xv10 : xv00, X1 = bt2 ? xv11 : xv01, X2 = bt2 ? xv12 : xv02;
        float ge[4];
        #pragma unroll
        for (int e = 0; e < 4; ++e)
          ge[e] = acc[e] + xwb[prow+e][0]*X0 + xwb[prow+e][1]*X1 + xwb[prow+e][2]*X2 + xwb[prow+e][3];
        const float iv = sigmoidf_(ge[0]);
        const float fv = sigmoidf_(ge[1]);
        const float gv = tanhf(ge[2]);
        const float ov = sigmoidf_(ge[3]);
        const float cprev = bt2 ? cr1 : cr0;
        const float cv = fmaf(fv, cprev, iv * gv);
        if (bt2) cr1 = cv; else cr0 = cv;
        const float hv = ov * tanhf(cv);
        hT[unit * 32 + batch] = hv;
        stb_u32(&pOut[(size_t)(b0 + batch) * HB + u0 + unit], pack_hl(hv));
      }
    }
    __syncthreads();                               // hT visible

    // ---- P6: exact-f32 p-partials -> own parity slot (no atomics) ----
    {
      float* ppsW = pps + (size_t)((t & 1) * NG + g) * (BPG * 960) + (size_t)ub * 960;
      PUBR(0) PUBR(1) PUBR(2) PUBR(3)
    }
    fence_vm();                                    // h stores + partial stores acked at IF
    __syncthreads();
    if (tid == 0) flag_add(c1l + (ub & 3) * 32);

    // ---- h_seq output AFTER flag (coalesced: 8B/thread, contiguous units) ----
    {
      const int b3 = tid >> 3, u2 = (tid & 7) * 2;
      float2 hv2 = make_float2(hT[u2 * 32 + b3], hT[(u2 + 1) * 32 + b3]);
      *(float2*)&out[OFF_H + ((size_t)(b0 + b3) * T_ + t) * H_ + u0 + u2] = hv2;
    }
  }
#undef GSTEP
#undef SUMR
#undef PUBR
}

extern "C" void kernel_launch(void* const* d_in, const int* in_sizes, int n_in,
                              void* d_out, int out_size, void* d_ws, size_t ws_size,
                              hipStream_t stream) {
  const float* x     = (const float*)d_in[0];
  const int*   sent  = (const int*)  d_in[1];
  const float* smask = (const float*)d_in[2];
  const float* W_ih  = (const float*)d_in[3];
  const float* W_hh  = (const float*)d_in[4];
  const float* b_ih  = (const float*)d_in[5];
  const float* b_hh  = (const float*)d_in[6];
  const float* W_win = (const float*)d_in[7];
  const float* b_win = (const float*)d_in[8];
  float* ws  = (float*)d_ws;
  float* out = (float*)d_out;

  hipLaunchKernelGGL(init_ws_kernel, dim3(512), dim3(256), 0, stream, ws);
  hipLaunchKernelGGL(graves_kernel, dim3(NG * BPG), dim3(NT), 0, stream,
                     x, sent, smask, W_ih, W_hh, b_ih, b_hh, W_win, b_win, out, ws);
}

// Round 13
// 12128.989 us; speedup vs baseline: 2.8091x; 2.8091x over previous
//
#include <hip/hip_runtime.h>
#include <hip/hip_bf16.h>
#include <math.h>

// Problem dims
#define B_   128
#define T_   800
#define H_   512
#define K_   10
#define C_   80
#define U_   64
#define IN_  3

// Decomposition: 4 groups x 32 batches; 32 blocks/group; each block owns 16 units (64 gate rows)
#define NG   4
#define BPG  32
#define BT   32
#define NT   256
#define KROW 608            // LDS padded K extent (592 real + 16 zero)
#define HB   512            // gbuf row width (h only; window never leaves the block)

// ws layout (4-byte units): gbuf[2][128][512] u32 | flags
#define WS_BAR_F   (2*B_*HB)
#define WS_TOTAL_F (WS_BAR_F + NG*4*32)

// out layout (f32 elements): h_seq | w_seq | phi_seq
#define OFF_H    0ull
#define OFF_W    ((size_t)B_ * T_ * H_)
#define OFF_PHI  (OFF_W + (size_t)B_ * T_ * C_)

typedef __attribute__((ext_vector_type(8))) short short8;
typedef __attribute__((ext_vector_type(4))) float f32x4;

// XOR swizzle of 16B units within each 64B span, keyed by row
#define SWZB(row)    (((row) ^ ((row) >> 2)) & 3)
#define SWIDX(row,k) ((row)*KROW + ((((k) >> 3) ^ SWZB(row)) << 3) + ((k) & 7))
#define LDFRAG(arr,row,u) (*(const short8*)&(arr)[(row)*KROW + (((u) ^ SWZB(row)) << 3)])

// ---- sync primitives (r5-proven recipe: bypass writes + vm fence + relaxed flags,
//      single poller + single acquire-inv per block-step, then plain cached loads) ----
__device__ __forceinline__ void stb_u32(unsigned* p, unsigned v) {
  asm volatile("global_store_dword %0, %1, off sc0 sc1" :: "v"(p), "v"(v) : "memory");
}
__device__ __forceinline__ void fence_vm() {
  asm volatile("s_waitcnt vmcnt(0)" ::: "memory");
}
__device__ __forceinline__ void flag_add(unsigned* p) {
  __hip_atomic_fetch_add(p, 1u, __ATOMIC_RELAXED, __HIP_MEMORY_SCOPE_AGENT);
}
__device__ __forceinline__ unsigned flag_sum4(unsigned* base) {
  unsigned s0 = __hip_atomic_load(base +  0, __ATOMIC_RELAXED, __HIP_MEMORY_SCOPE_AGENT);
  unsigned s1 = __hip_atomic_load(base + 32, __ATOMIC_RELAXED, __HIP_MEMORY_SCOPE_AGENT);
  unsigned s2 = __hip_atomic_load(base + 64, __ATOMIC_RELAXED, __HIP_MEMORY_SCOPE_AGENT);
  unsigned s3 = __hip_atomic_load(base + 96, __ATOMIC_RELAXED, __HIP_MEMORY_SCOPE_AGENT);
  return (s0 + s1) + (s2 + s3);
}
__device__ __forceinline__ void acq_fence(unsigned* p) {
  (void)__hip_atomic_load(p, __ATOMIC_ACQUIRE, __HIP_MEMORY_SCOPE_AGENT);
}
__device__ __forceinline__ float sigmoidf_(float v) { return 1.0f / (1.0f + expf(-v)); }
__device__ __forceinline__ unsigned pack_hl(float v) {
  unsigned hb = __float_as_uint(v) >> 16;
  float rs = v - __uint_as_float(hb << 16);
  unsigned lb = __float_as_uint(rs) >> 16;
  return (hb << 16) | lb;
}
__device__ __forceinline__ float comb_hl(short h, short l) {
  return __uint_as_float((unsigned)(unsigned short)h << 16) +
         __uint_as_float((unsigned)(unsigned short)l << 16);
}

__global__ void __launch_bounds__(256, 2)
init_ws_kernel(float* __restrict__ ws) {
  size_t i = (size_t)blockIdx.x * 256 + threadIdx.x;
  const size_t n = (size_t)WS_TOTAL_F;
  const size_t stride = (size_t)gridDim.x * 256;
  for (; i < n; i += stride) ws[i] = 0.0f;
}

__global__ void __launch_bounds__(NT, 1)
graves_kernel(const float* __restrict__ x,       // [B][T][3]
              const int*   __restrict__ sent,    // [B][U]
              const float* __restrict__ smask,   // [B][U]
              const float* __restrict__ W_ih,    // [2048][83]
              const float* __restrict__ W_hh,    // [2048][512]
              const float* __restrict__ b_ih,    // [2048]
              const float* __restrict__ b_hh,    // [2048]
              const float* __restrict__ W_win,   // [30][512]
              const float* __restrict__ b_win,   // [30]
              float* __restrict__ out,
              float* __restrict__ ws)
{
  const int tid = threadIdx.x;
  const int bid = blockIdx.x;
  // XCD-local grouping heuristic: group g on XCDs {2g,2g+1} (any bijection is correct).
  const int xcd  = bid & 7, slot = bid >> 3;     // slot 0..15
  const int g    = xcd >> 1;
  const int ub   = ((xcd & 1) << 4) | slot;      // 0..31  (== the batch this block writes)
  const int b0   = g * BT;
  const int u0   = ub * 16;                      // first unit owned

  unsigned* gbuf = (unsigned*)ws;
  unsigned* c1l  = (unsigned*)(ws + WS_BAR_F) + (size_t)g * 128;  // 4 lines x 8 arrivals/step

  // ---- LDS: 150,528 B -> 1 block/CU ----
  __shared__ __align__(16) short shi[32 * KROW];   // 38,912 B  state hi
  __shared__ __align__(16) short slo[32 * KROW];   // 38,912 B  state lo
  __shared__ __align__(16) short wwf[2*16*2*64*8]; // 65,536 B  W_win A-frags (pre-permuted, split)
  __shared__ float pbufS[32][32];                  //  4,096 B  p / window params
  __shared__ float hT[16 * 32];                    //  2,048 B  own units' exact f32 h [unit][batch]
  __shared__ float xwb[64][4];                     //  1,024 B  x-weights + bias per gate row

  // wave identity
  const int lane = tid & 63;
  const int wid  = tid >> 6;         // 4 waves; wave owns gate rows wid*16..wid*16+15 (full k)
  const int r16  = lane & 15;
  const int g4   = lane >> 4;

  // ---- one-time LDS staging ----
  for (int idx = tid; idx < 32 * 16; idx += NT) {  // zero state pad cols 592..607 (never rewritten)
    const int b2 = idx >> 4, k = (H_ + C_) + (idx & 15);
    shi[SWIDX(b2, k)] = 0; slo[SWIDX(b2, k)] = 0;
  }
  if (tid < 64) {                                   // xwb: row = unit_l*4 + gate
    const int uu = tid >> 2, gate = tid & 3, gr = gate * H_ + u0 + uu;
    xwb[tid][0] = W_ih[(size_t)gr * (IN_ + C_) + 0];
    xwb[tid][1] = W_ih[(size_t)gr * (IN_ + C_) + 1];
    xwb[tid][2] = W_ih[(size_t)gr * (IN_ + C_) + 2];
    xwb[tid][3] = b_ih[gr] + b_hh[gr];
  }
  // W_win A-frags: frag(tt,ks,hl): lane L holds row tt*16+(L&15), k = ks*32+(L>>4)*8+e
  for (int idx = tid; idx < 2 * 16 * 2 * 64; idx += NT) {
    const int ln = idx & 63, hl = (idx >> 6) & 1, ks = (idx >> 7) & 15, tt = idx >> 11;
    const int j = tt * 16 + (ln & 15);
    short v8[8];
    #pragma unroll
    for (int e = 0; e < 8; ++e) {
      const int k = ks * 32 + (ln >> 4) * 8 + e;
      const float wv = (j < 30) ? W_win[(size_t)j * H_ + k] : 0.0f;
      const unsigned hb = __float_as_uint(wv) >> 16;
      const float rs = wv - __uint_as_float(hb << 16);
      v8[e] = hl ? (short)(__float_as_uint(rs) >> 16) : (short)hb;
    }
    #pragma unroll
    for (int e = 0; e < 8; ++e) wwf[idx * 8 + e] = v8[e];
  }

  // ---- one-time: gate-weight A-fragments -> persistent VGPRs (split bf16, 152 VGPRs) ----
  short8 wh[19], wl[19];
  {
    const int lrow = wid * 16 + r16;
    const int uuA = lrow >> 2, gateA = lrow & 3;
    const int gr = gateA * H_ + u0 + uuA;
    #pragma unroll
    for (int ks = 0; ks < 19; ++ks) {
      short8 h8 = {0,0,0,0,0,0,0,0}, l8 = h8;
      #pragma unroll
      for (int e = 0; e < 8; ++e) {
        const int k = ks * 32 + g4 * 8 + e;
        float wv = 0.0f;
        if (k < H_)           wv = W_hh[(size_t)gr * H_ + k];
        else if (k < H_ + C_) wv = W_ih[(size_t)gr * (IN_ + C_) + IN_ + (k - H_)];
        const unsigned hb = __float_as_uint(wv) >> 16;
        const float rs = wv - __uint_as_float(hb << 16);
        h8[e] = (short)hb; l8[e] = (short)(__float_as_uint(rs) >> 16);
      }
      wh[ks] = h8; wl[ks] = l8;
    }
  }

  // ---- per-thread sent/mask for phi/scatter: thread = (pb = tid>>3, ug = tid&7), u = ug*8+i ----
  const int pb = tid >> 3, ug = tid & 7;
  float msk[8]; int snt[8];
  #pragma unroll
  for (int i = 0; i < 8; ++i) {
    msk[i] = smask[(size_t)(b0 + pb) * U_ + ug * 8 + i];
    snt[i] = sent [(size_t)(b0 + pb) * U_ + ug * 8 + i];
  }
  __syncthreads();

  float cr0 = 0.0f, cr1 = 0.0f;      // c-state (per thread: unit wid*4+g4, batches r16 / 16+r16)
  float kp0 = 0.f, kp1 = 0.f, kp2 = 0.f, kp3 = 0.f;  // kappa regs (fixed item->thread mapping)

#define GSTEP(ks) { \
    const int uu_ = (ks) * 4 + g4; \
    const short8 bh0 = LDFRAG(shi, r16, uu_); \
    const short8 bl0 = LDFRAG(slo, r16, uu_); \
    const short8 bh1 = LDFRAG(shi, 16 + r16, uu_); \
    const short8 bl1 = LDFRAG(slo, 16 + r16, uu_); \
    a0 = __builtin_amdgcn_mfma_f32_16x16x32_bf16(wh[ks], bh0, a0, 0, 0, 0); \
    a0 = __builtin_amdgcn_mfma_f32_16x16x32_bf16(wh[ks], bl0, a0, 0, 0, 0); \
    a0 = __builtin_amdgcn_mfma_f32_16x16x32_bf16(wl[ks], bh0, a0, 0, 0, 0); \
    a1 = __builtin_amdgcn_mfma_f32_16x16x32_bf16(wh[ks], bh1, a1, 0, 0, 0); \
    a1 = __builtin_amdgcn_mfma_f32_16x16x32_bf16(wh[ks], bl1, a1, 0, 0, 0); \
    a1 = __builtin_amdgcn_mfma_f32_16x16x32_bf16(wl[ks], bh1, a1, 0, 0, 0); \
  }

#define EXPR(r, KP) { \
    const int item = tid + 256 * (r); \
    if (item < 960) { \
      const int b2 = item / 30, j = item - b2 * 30; \
      float ev = __expf(pbufS[b2][j] + b_win[j]); \
      if (j >= 20) { ev += (KP); (KP) = ev; } \
      pbufS[b2][j] = ev; \
    } }

  for (int t = 0; t <= T_; ++t) {
    const unsigned* pIn  = gbuf + (size_t)((t & 1) ^ 1) * (B_ * HB);
    unsigned*       pOut = gbuf + (size_t)(t & 1) * (B_ * HB);

    // ---- P1: single sync point, 32-wide; single poller, single acquire-inv ----
    if (t > 0 && tid == 0) {
      const unsigned tgt = 32u * (unsigned)t;
      while (flag_sum4(c1l) < tgt) __builtin_amdgcn_s_sleep(1);
      acq_fence(c1l);
    }
    __syncthreads();

    // ---- P2: stage h(t-1) into LDS (split bf16, swizzled); zero window cols; x prefetch ----
    float xv00=0.f,xv01=0.f,xv02=0.f, xv10=0.f,xv11=0.f,xv12=0.f;
    {
      const int sb = tid & 31, seg = tid >> 5;     // 8 segs x 64 k  (stage ALWAYS, incl. t==T)
      const uint4* grow = (const uint4*)(pIn + (size_t)(b0 + sb) * HB + seg * 64);
      #pragma unroll
      for (int half = 0; half < 2; ++half) {
        uint4 v[8];
        #pragma unroll
        for (int i = 0; i < 8; ++i) v[i] = grow[half * 8 + i];
        #pragma unroll
        for (int i = 0; i < 8; ++i) {
          const int k = seg * 64 + half * 32 + i * 4;
          const int idx = SWIDX(sb, k);
          const unsigned h01 = (v[i].x >> 16) | ((v[i].y >> 16) << 16);
          const unsigned h23 = (v[i].z >> 16) | ((v[i].w >> 16) << 16);
          const unsigned l01 = (v[i].x & 0xffffu) | ((v[i].y & 0xffffu) << 16);
          const unsigned l23 = (v[i].z & 0xffffu) | ((v[i].w & 0xffffu) << 16);
          *(uint2*)&shi[idx] = make_uint2(h01, h23);
          *(uint2*)&slo[idx] = make_uint2(l01, l23);
        }
      }
      #pragma unroll
      for (int i = 0; i < 10; ++i) {               // zero window cols (scatter accumulates)
        const int c = seg * 10 + i;
        const int idx = SWIDX(sb, H_ + c);
        shi[idx] = 0; slo[idx] = 0;
      }
      if (t < T_) {
        const float* xp0 = x + ((size_t)(b0 + r16) * T_ + t) * IN_;
        const float* xp1 = x + ((size_t)(b0 + 16 + r16) * T_ + t) * IN_;
        xv00 = xp0[0]; xv01 = xp0[1]; xv02 = xp0[2];
        xv10 = xp1[0]; xv11 = xp1[1]; xv12 = xp1[2];
      }
    }
    __syncthreads();

    // ---- P3: window(t-1), computed redundantly & bitwise-identically by every block ----
    if (t >= 1) {
      // p = W_win · s  via 4-term full-split MFMA (exact products, f32 accumulate)
      {
        const int rt = wid & 1, btile = wid >> 1;  // wave -> (row-tile, batch-tile)
        f32x4 pa = {0.f, 0.f, 0.f, 0.f};
        #pragma unroll
        for (int ks = 0; ks < 16; ++ks) {
          const short8 awh = *(const short8*)&wwf[(((rt * 16 + ks) * 2 + 0) * 64 + lane) * 8];
          const short8 awl = *(const short8*)&wwf[(((rt * 16 + ks) * 2 + 1) * 64 + lane) * 8];
          const int uu_ = ks * 4 + g4;
          const short8 bh = LDFRAG(shi, btile * 16 + r16, uu_);
          const short8 bl = LDFRAG(slo, btile * 16 + r16, uu_);
          pa = __builtin_amdgcn_mfma_f32_16x16x32_bf16(awh, bh, pa, 0, 0, 0);
          pa = __builtin_amdgcn_mfma_f32_16x16x32_bf16(awh, bl, pa, 0, 0, 0);
          pa = __builtin_amdgcn_mfma_f32_16x16x32_bf16(awl, bh, pa, 0, 0, 0);
          pa = __builtin_amdgcn_mfma_f32_16x16x32_bf16(awl, bl, pa, 0, 0, 0);
        }
        #pragma unroll
        for (int e = 0; e < 4; ++e) {              // D: col=lane&15 (batch), row=(lane>>4)*4+e
          const int j = rt * 16 + g4 * 4 + e;
          if (j < 30) pbufS[btile * 16 + r16][j] = pa[e];
        }
      }
      __syncthreads();

      // exp + kappa accumulate (register-held, fixed thread->item map => deterministic)
      EXPR(0, kp0) EXPR(1, kp1) EXPR(2, kp2) EXPR(3, kp3)
      __syncthreads();

      // phi per (pb, ug): 8 u-values; params hoisted to registers
      float al[10], be[10], ka[10];
      #pragma unroll
      for (int k2 = 0; k2 < 10; ++k2) {
        al[k2] = pbufS[pb][k2];
        be[k2] = pbufS[pb][10 + k2];
        ka[k2] = pbufS[pb][20 + k2];
      }
      float ph[8];
      #pragma unroll
      for (int i = 0; i < 8; ++i) {
        const float fu = (float)(ug * 8 + i);
        float s = 0.0f;
        #pragma unroll
        for (int k2 = 0; k2 < 10; ++k2) {
          const float d = ka[k2] - fu;
          s = fmaf(al[k2], __expf(-be[k2] * d * d), s);
        }
        ph[i] = s;
      }
      if (pb == ub) {                              // raw phi out (block's batch)
        #pragma unroll
        for (int i = 0; i < 8; ++i)
          out[OFF_PHI + ((size_t)(b0 + pb) * T_ + (t - 1)) * U_ + ug * 8 + i] = ph[i];
      }
      #pragma unroll
      for (int i = 0; i < 8; ++i) ph[i] *= msk[i];

      // scatter into state LDS window cols (split hi/lo). Rounds over ug serialize
      // same-row writers (waves own disjoint pb rows; DS ops within a wave are ordered).
      #pragma unroll
      for (int r = 0; r < 8; ++r) {
        if (ug == r) {
          #pragma unroll
          for (int i = 0; i < 8; ++i) {
            const int idx = SWIDX(pb, H_ + snt[i]);
            float cur = comb_hl(shi[idx], slo[idx]) + ph[i];
            const unsigned pk = pack_hl(cur);
            shi[idx] = (short)(pk >> 16);
            slo[idx] = (short)(pk & 0xffffu);
          }
        }
        asm volatile("" ::: "memory");
      }
      __syncthreads();
      if (tid < C_) {                              // window out (block's batch)
        const int idx = SWIDX(ub, H_ + tid);
        out[OFF_W + ((size_t)(b0 + ub) * T_ + (t - 1)) * C_ + tid] = comb_hl(shi[idx], slo[idx]);
      }
    }
    if (t == T_) break;                            // epilogue done

    // ---- P4: full gate GEMM, k 0..607; wave owns 16 rows x full k ----
    f32x4 a0 = {0.f, 0.f, 0.f, 0.f}, a1 = {0.f, 0.f, 0.f, 0.f};
    GSTEP(0)  GSTEP(1)  GSTEP(2)  GSTEP(3)  GSTEP(4)
    GSTEP(5)  GSTEP(6)  GSTEP(7)  GSTEP(8)  GSTEP(9)
    GSTEP(10) GSTEP(11) GSTEP(12) GSTEP(13) GSTEP(14)
    GSTEP(15) GSTEP(16) GSTEP(17) GSTEP(18)

    // ---- P5: LSTM pointwise, wave-local (D row = g4*4+e => unit wid*4+g4, gate e) ----
    {
      const int unit = wid * 4 + g4;
      const int prow = wid * 16 + g4 * 4;
      #pragma unroll
      for (int bt2 = 0; bt2 < 2; ++bt2) {
        const f32x4 acc = bt2 ? a1 : a0;
        const int batch = bt2 * 16 + r16;
        const float X0 = bt2 ? xv10 : xv00, X1 = bt2 ? xv11 : xv01, X2 = bt2 ? xv12 : xv02;
        float ge[4];
        #pragma unroll
        for (int e = 0; e < 4; ++e)
          ge[e] = acc[e] + xwb[prow+e][0]*X0 + xwb[prow+e][1]*X1 + xwb[prow+e][2]*X2 + xwb[prow+e][3];
        const float iv = sigmoidf_(ge[0]);
        const float fv = sigmoidf_(ge[1]);
        const float gv = tanhf(ge[2]);
        const float ov = sigmoidf_(ge[3]);
        const float cprev = bt2 ? cr1 : cr0;
        const float cv = fmaf(fv, cprev, iv * gv);
        if (bt2) cr1 = cv; else cr0 = cv;
        const float hv = ov * tanhf(cv);
        hT[unit * 32 + batch] = hv;
        stb_u32(&pOut[(size_t)(b0 + batch) * HB + u0 + unit], pack_hl(hv));
      }
    }
    fence_vm();                                    // h stores acked at IF (per-wave)
    __syncthreads();
    if (tid == 0) flag_add(c1l + (ub & 3) * 32);

    // ---- h_seq output AFTER flag (coalesced: 8B/thread, contiguous units) ----
    {
      const int b3 = tid >> 3, u2 = (tid & 7) * 2;
      float2 hv2 = make_float2(hT[u2 * 32 + b3], hT[(u2 + 1) * 32 + b3]);
      *(float2*)&out[OFF_H + ((size_t)(b0 + b3) * T_ + t) * H_ + u0 + u2] = hv2;
    }
  }
#undef GSTEP
#undef EXPR
}

extern "C" void kernel_launch(void* const* d_in, const int* in_sizes, int n_in,
                              void* d_out, int out_size, void* d_ws, size_t ws_size,
                              hipStream_t stream) {
  const float* x     = (const float*)d_in[0];
  const int*   sent  = (const int*)  d_in[1];
  const float* smask = (const float*)d_in[2];
  const float* W_ih  = (const float*)d_in[3];
  const float* W_hh  = (const float*)d_in[4];
  const float* b_ih  = (const float*)d_in[5];
  const float* b_hh  = (const float*)d_in[6];
  const float* W_win = (const float*)d_in[7];
  const float* b_win = (const float*)d_in[8];
  float* ws  = (float*)d_ws;
  float* out = (float*)d_out;

  hipLaunchKernelGGL(init_ws_kernel, dim3(512), dim3(256), 0, stream, ws);
  hipLaunchKernelGGL(graves_kernel, dim3(NG * BPG), dim3(NT), 0, stream,
                     x, sent, smask, W_ih, W_hh, b_ih, b_hh, W_win, b_win, out, ws);
}